// Round 1
// baseline (201.940 us; speedup 1.0000x reference)
//
#include <hip/hip_runtime.h>
#include <math.h>

#define NG 64
#define NPG 128
#define DF 64
#define NN (NG * NPG)   // 8192
#define NE 131072

// ---- degree: one float atomicAdd per edge endpoint (exact for small ints)
__global__ void deg_kernel(const int* __restrict__ ei, float* __restrict__ deg) {
    int i = blockIdx.x * 256 + threadIdx.x;
    atomicAdd(&deg[ei[i]], 1.0f);
    atomicAdd(&deg[ei[NE + i]], 1.0f);
}

// ---- per-node squared norm, fp32, float4 loads
__global__ void sq_kernel(const float* __restrict__ x, float* __restrict__ sq) {
    int i = blockIdx.x * 256 + threadIdx.x;
    const float4* xv = (const float4*)(x + (size_t)i * DF);
    float s = 0.f;
#pragma unroll
    for (int k = 0; k < 16; ++k) {
        float4 v = xv[k];
        s = fmaf(v.x, v.x, s);
        s = fmaf(v.y, v.y, s);
        s = fmaf(v.z, v.z, s);
        s = fmaf(v.w, v.w, s);
    }
    sq[i] = s;
}

// ---- main: one block per (g,h) pair. 128x128 sim tile, 8x8 regs/thread.
// LDS XOR-swizzle (phys float4 col = c ^ (row&15)) + strided tiles
// (rows ty+16i, cols tx+16j) -> conflict-clean ds_read_b128 fragments.
__global__ __launch_bounds__(256, 2) void sim_kernel(
    const float* __restrict__ x, const float* __restrict__ deg,
    const float* __restrict__ sq, float* __restrict__ mp) {
    __shared__ __align__(16) float As[NPG * DF];
    __shared__ __align__(16) float Bs[NPG * DF];
    __shared__ float dA[NPG], dB[NPG], qA[NPG], qB[NPG];
    __shared__ float rowpart[16];
    __shared__ float colpart[4 * NPG];
    __shared__ float redbuf[2];

    const int h = blockIdx.x, g = blockIdx.y;
    const int t = threadIdx.x;
    const int tx = t & 15, ty = t >> 4;

    // stage A (graph g) and B (graph h) into LDS, swizzled
    const float4* gx = (const float4*)x;
#pragma unroll
    for (int it = 0; it < 8; ++it) {
        int idx = it * 256 + t;       // 0..2047
        int r = idx >> 4, c = idx & 15;
        float4 av = gx[(g * NPG + r) * 16 + c];
        float4 bv = gx[(h * NPG + r) * 16 + c];
        int pc = c ^ (r & 15);
        *(float4*)&As[r * DF + pc * 4] = av;
        *(float4*)&Bs[r * DF + pc * 4] = bv;
    }
    if (t < 128) {
        dA[t] = deg[g * NPG + t];
        qA[t] = sq[g * NPG + t];
    } else {
        int u = t - 128;
        dB[u] = deg[h * NPG + u];
        qB[u] = sq[h * NPG + u];
    }
    __syncthreads();

    float acc[8][8];
#pragma unroll
    for (int i = 0; i < 8; ++i)
#pragma unroll
        for (int j = 0; j < 8; ++j) acc[i][j] = 0.f;

    for (int dc = 0; dc < 16; ++dc) {
        float4 ar[8], br[8];
        int pa = (dc ^ ty) << 2;
        int pb = (dc ^ tx) << 2;
#pragma unroll
        for (int i = 0; i < 8; ++i)
            ar[i] = *(const float4*)&As[(ty + i * 16) * DF + pa];
#pragma unroll
        for (int j = 0; j < 8; ++j)
            br[j] = *(const float4*)&Bs[(tx + j * 16) * DF + pb];
#pragma unroll
        for (int i = 0; i < 8; ++i)
#pragma unroll
            for (int j = 0; j < 8; ++j) {
                acc[i][j] = fmaf(ar[i].x, br[j].x, acc[i][j]);
                acc[i][j] = fmaf(ar[i].y, br[j].y, acc[i][j]);
                acc[i][j] = fmaf(ar[i].z, br[j].z, acc[i][j]);
                acc[i][j] = fmaf(ar[i].w, br[j].w, acc[i][j]);
            }
    }

    float qa[8], da[8], qb[8], db[8];
#pragma unroll
    for (int i = 0; i < 8; ++i) {
        qa[i] = qA[ty + i * 16];
        da[i] = dA[ty + i * 16];
    }
#pragma unroll
    for (int j = 0; j < 8; ++j) {
        qb[j] = qB[tx + j * 16];
        db[j] = dB[tx + j * 16];
    }

    // sim = exp(2*acc - (qa + qb + (da-db)^2)); track row/col maxes
    float rmax[8], cmax[8];
#pragma unroll
    for (int i = 0; i < 8; ++i) { rmax[i] = 0.f; cmax[i] = 0.f; }
#pragma unroll
    for (int i = 0; i < 8; ++i) {
#pragma unroll
        for (int j = 0; j < 8; ++j) {
            float dd = da[i] - db[j];
            float tv = qa[i] + qb[j] + dd * dd;
            float s = __expf(fmaf(2.f, acc[i][j], -tv));
            rmax[i] = fmaxf(rmax[i], s);
            cmax[j] = fmaxf(cmax[j], s);
        }
    }

    // row maxes: reduce across tx (16 consecutive lanes)
#pragma unroll
    for (int off = 1; off < 16; off <<= 1)
#pragma unroll
        for (int i = 0; i < 8; ++i)
            rmax[i] = fmaxf(rmax[i], __shfl_xor(rmax[i], off, 64));
    if (tx == 0) {
        float s = 0.f;
#pragma unroll
        for (int i = 0; i < 8; ++i) s += rmax[i];
        rowpart[ty] = s;  // rows ty+16i, all i
    }

    // col maxes: reduce across the 4 ty values within each wave, then LDS
#pragma unroll
    for (int off = 16; off < 64; off <<= 1)
#pragma unroll
        for (int j = 0; j < 8; ++j)
            cmax[j] = fmaxf(cmax[j], __shfl_xor(cmax[j], off, 64));
    int wv = t >> 6;
    if ((t & 63) < 16) {
#pragma unroll
        for (int j = 0; j < 8; ++j)
            colpart[wv * NPG + tx + j * 16] = cmax[j];
    }
    __syncthreads();

    if (t < 128) {
        float cm = colpart[t];
#pragma unroll
        for (int w = 1; w < 4; ++w) cm = fmaxf(cm, colpart[w * NPG + t]);
#pragma unroll
        for (int off = 1; off < 64; off <<= 1)
            cm += __shfl_xor(cm, off, 64);
        if ((t & 63) == 0) redbuf[t >> 6] = cm;
    }
    __syncthreads();
    if (t == 0) {
        float mrow = 0.f;
#pragma unroll
        for (int k = 0; k < 16; ++k) mrow += rowpart[k];
        float mcol = redbuf[0] + redbuf[1];
        mp[g * NG + h] = 0.5f * (mrow + mcol);  // 0.5*(m_row+m_col)
    }
}

// ---- epilogue: match = 0.5*(mp + mp^T); dist = lam*(n - match), zero diag
__global__ void out_kernel(const float* __restrict__ mp,
                           const float* __restrict__ lam_raw,
                           float* __restrict__ out) {
    int i = blockIdx.x * 256 + threadIdx.x;
    int g = i >> 6, hh = i & 63;
    float lam = log1pf(expf(lam_raw[0]));  // softplus
    float m = 0.5f * (mp[g * NG + hh] + mp[hh * NG + g]);
    out[i] = (g == hh) ? 0.f : lam * ((float)NPG - m);
}

extern "C" void kernel_launch(void* const* d_in, const int* in_sizes, int n_in,
                              void* d_out, int out_size, void* d_ws, size_t ws_size,
                              hipStream_t stream) {
    const float* x = (const float*)d_in[0];
    const int* ei = (const int*)d_in[1];
    const float* lam_raw = (const float*)d_in[4];

    float* deg = (float*)d_ws;        // [8192]
    float* sq = deg + NN;             // [8192]
    float* mp = sq + NN;              // [4096]

    hipMemsetAsync(d_ws, 0, NN * sizeof(float), stream);  // zero deg (ws is poisoned)
    deg_kernel<<<NE / 256, 256, 0, stream>>>(ei, deg);
    sq_kernel<<<NN / 256, 256, 0, stream>>>(x, sq);
    dim3 grid(NG, NG);
    sim_kernel<<<grid, 256, 0, stream>>>(x, deg, sq, mp);
    out_kernel<<<(NG * NG) / 256, 256, 0, stream>>>(mp, lam_raw, (float*)d_out);
}

// Round 2
// 102.297 us; speedup vs baseline: 1.9741x; 1.9741x over previous
//
#include <hip/hip_runtime.h>
#include <math.h>

#define NG 64
#define NPG 128
#define DF 64
#define NN (NG * NPG)   // 8192
#define NE 131072
#define NPAIR 2016      // 64*63/2 unordered pairs g<h
#define LDA 72          // bf16 elems per LDS row: 64 + 8 pad (144 B, 16B-aligned)

typedef __attribute__((ext_vector_type(8))) short short8;   // 8 bf16 = 4 VGPRs
typedef __attribute__((ext_vector_type(4))) float f32x4;

static __device__ __forceinline__ unsigned short f2bf(float f) {
    unsigned u = __builtin_bit_cast(unsigned, f);
    return (unsigned short)((u + 0x7FFFu + ((u >> 16) & 1u)) >> 16);  // RNE
}

// ---- degree: one float atomicAdd per edge endpoint (exact for small ints)
__global__ void deg_kernel(const int* __restrict__ ei, float* __restrict__ deg) {
    int i = blockIdx.x * 256 + threadIdx.x;
    atomicAdd(&deg[ei[i]], 1.0f);
    atomicAdd(&deg[ei[NE + i]], 1.0f);
}

// ---- per-node squared norm, fp32, float4 loads
__global__ void sq_kernel(const float* __restrict__ x, float* __restrict__ sq) {
    int i = blockIdx.x * 256 + threadIdx.x;
    const float4* xv = (const float4*)(x + (size_t)i * DF);
    float s = 0.f;
#pragma unroll
    for (int k = 0; k < 16; ++k) {
        float4 v = xv[k];
        s = fmaf(v.x, v.x, s);
        s = fmaf(v.y, v.y, s);
        s = fmaf(v.z, v.z, s);
        s = fmaf(v.w, v.w, s);
    }
    sq[i] = s;
}

// ---- main: one block per unordered pair (g<h). Gram via bf16 MFMA 16x16x32.
// 4 waves; wave w owns C-rows 32w..32w+31 (2 tile-rows x 8 tile-cols).
__global__ __launch_bounds__(256, 2) void sim_kernel(
    const float* __restrict__ x, const float* __restrict__ deg,
    const float* __restrict__ sq, const float* __restrict__ lam_raw,
    float* __restrict__ out) {
    __shared__ __align__(16) unsigned short As[NPG * LDA];
    __shared__ __align__(16) unsigned short Bs[NPG * LDA];
    __shared__ float dA[NPG], qA[NPG], dB[NPG], qB[NPG];
    __shared__ float rowpart[4];
    __shared__ float colpart[4 * NPG];
    __shared__ float redbuf[2];

    const int t = threadIdx.x;

    // decode blockIdx -> (g,h), g<h (triangular, reversed enumeration)
    int j = (NPAIR - 1) - (int)blockIdx.x;
    int r = (int)((sqrtf((float)(8 * j + 1)) - 1.0f) * 0.5f);
    while ((r + 1) * (r + 2) / 2 <= j) ++r;
    while (r * (r + 1) / 2 > j) --r;
    const int g = 62 - r;
    const int h = 63 - (j - r * (r + 1) / 2);

    // stage both 128x64 fp32 blocks into LDS as bf16 (padded rows)
#pragma unroll
    for (int it = 0; it < 4; ++it) {
        int idx = it * 256 + t;      // 0..1023 granules of 8 floats
        int rr = idx >> 3, cc = idx & 7;
        const float4* pa = (const float4*)(x + ((size_t)(g * NPG + rr) * DF + cc * 8));
        const float4* pb = (const float4*)(x + ((size_t)(h * NPG + rr) * DF + cc * 8));
        float4 a0 = pa[0], a1 = pa[1];
        float4 b0 = pb[0], b1 = pb[1];
        union { unsigned short us[8]; uint4 v; } ua, ub;
        ua.us[0] = f2bf(a0.x); ua.us[1] = f2bf(a0.y); ua.us[2] = f2bf(a0.z); ua.us[3] = f2bf(a0.w);
        ua.us[4] = f2bf(a1.x); ua.us[5] = f2bf(a1.y); ua.us[6] = f2bf(a1.z); ua.us[7] = f2bf(a1.w);
        ub.us[0] = f2bf(b0.x); ub.us[1] = f2bf(b0.y); ub.us[2] = f2bf(b0.z); ub.us[3] = f2bf(b0.w);
        ub.us[4] = f2bf(b1.x); ub.us[5] = f2bf(b1.y); ub.us[6] = f2bf(b1.z); ub.us[7] = f2bf(b1.w);
        *(uint4*)&As[rr * LDA + cc * 8] = ua.v;
        *(uint4*)&Bs[rr * LDA + cc * 8] = ub.v;
    }
    if (t < 128) {
        dA[t] = deg[g * NPG + t];
        qA[t] = sq[g * NPG + t];
    } else {
        int u = t - 128;
        dB[u] = deg[h * NPG + u];
        qB[u] = sq[h * NPG + u];
    }
    __syncthreads();

    const int L = t & 63, w = t >> 6;
    const int tx = L & 15, q = L >> 4;

    f32x4 acc[2][8];
#pragma unroll
    for (int tr = 0; tr < 2; ++tr)
#pragma unroll
        for (int tc = 0; tc < 8; ++tc) acc[tr][tc] = (f32x4){0.f, 0.f, 0.f, 0.f};

    // K = 64 = 2 halves of 32. A/B operand: elem row = lane&15, k = quad*8+j.
#pragma unroll
    for (int kh = 0; kh < 2; ++kh) {
        int ko = kh * 32 + q * 8;
        short8 a0 = *(const short8*)&As[(w * 32 + tx) * LDA + ko];
        short8 a1 = *(const short8*)&As[(w * 32 + 16 + tx) * LDA + ko];
        short8 bfr[8];
#pragma unroll
        for (int tc = 0; tc < 8; ++tc)
            bfr[tc] = *(const short8*)&Bs[(tc * 16 + tx) * LDA + ko];
#pragma unroll
        for (int tc = 0; tc < 8; ++tc)
            acc[0][tc] = __builtin_amdgcn_mfma_f32_16x16x32_bf16(a0, bfr[tc], acc[0][tc], 0, 0, 0);
#pragma unroll
        for (int tc = 0; tc < 8; ++tc)
            acc[1][tc] = __builtin_amdgcn_mfma_f32_16x16x32_bf16(a1, bfr[tc], acc[1][tc], 0, 0, 0);
    }

    // C/D layout: col = lane&15, row = quad*4 + reg
    float qa[2][4], da[2][4];
#pragma unroll
    for (int tr = 0; tr < 2; ++tr)
#pragma unroll
        for (int v = 0; v < 4; ++v) {
            int ra = w * 32 + tr * 16 + q * 4 + v;
            qa[tr][v] = qA[ra];
            da[tr][v] = dA[ra];
        }
    float qb[8], db[8];
#pragma unroll
    for (int tc = 0; tc < 8; ++tc) {
        int cb = tc * 16 + tx;
        qb[tc] = qB[cb];
        db[tc] = dB[cb];
    }

    float rmax[2][4], cmax[8];
#pragma unroll
    for (int tr = 0; tr < 2; ++tr)
#pragma unroll
        for (int v = 0; v < 4; ++v) rmax[tr][v] = 0.f;
#pragma unroll
    for (int tc = 0; tc < 8; ++tc) cmax[tc] = 0.f;

#pragma unroll
    for (int tr = 0; tr < 2; ++tr)
#pragma unroll
        for (int tc = 0; tc < 8; ++tc)
#pragma unroll
            for (int v = 0; v < 4; ++v) {
                float dd = da[tr][v] - db[tc];
                float tv = qa[tr][v] + qb[tc] + dd * dd;
                float s = __expf(fmaf(2.f, acc[tr][tc][v], -tv));
                rmax[tr][v] = fmaxf(rmax[tr][v], s);
                cmax[tc] = fmaxf(cmax[tc], s);
            }

    // row maxes: butterfly over the 16 cols (lanes sharing quad)
#pragma unroll
    for (int off = 1; off < 16; off <<= 1)
#pragma unroll
        for (int tr = 0; tr < 2; ++tr)
#pragma unroll
            for (int v = 0; v < 4; ++v)
                rmax[tr][v] = fmaxf(rmax[tr][v], __shfl_xor(rmax[tr][v], off, 64));
    float rsum = 0.f;
#pragma unroll
    for (int tr = 0; tr < 2; ++tr)
#pragma unroll
        for (int v = 0; v < 4; ++v) rsum += rmax[tr][v];
    rsum += __shfl_xor(rsum, 16, 64);
    rsum += __shfl_xor(rsum, 32, 64);   // now = sum of this wave's 32 row-maxes
    if (L == 0) rowpart[w] = rsum;

    // col maxes: butterfly across quads, then LDS across waves
#pragma unroll
    for (int off = 16; off < 64; off <<= 1)
#pragma unroll
        for (int tc = 0; tc < 8; ++tc)
            cmax[tc] = fmaxf(cmax[tc], __shfl_xor(cmax[tc], off, 64));
    if (L < 16) {
#pragma unroll
        for (int tc = 0; tc < 8; ++tc)
            colpart[w * NPG + tc * 16 + L] = cmax[tc];
    }
    __syncthreads();

    if (t < 128) {
        float cm = colpart[t];
#pragma unroll
        for (int w2 = 1; w2 < 4; ++w2) cm = fmaxf(cm, colpart[w2 * NPG + t]);
#pragma unroll
        for (int off = 1; off < 64; off <<= 1)
            cm += __shfl_xor(cm, off, 64);
        if ((t & 63) == 0) redbuf[t >> 6] = cm;
    }
    __syncthreads();
    if (t == 0) {
        float mrow = rowpart[0] + rowpart[1] + rowpart[2] + rowpart[3];
        float mcol = redbuf[0] + redbuf[1];
        float M = 0.5f * (mrow + mcol);   // == final symmetrized match[g,h]
        float lam = log1pf(expf(lam_raw[0]));
        float dv = lam * ((float)NPG - M);
        out[g * NG + h] = dv;
        out[h * NG + g] = dv;
    }
}

extern "C" void kernel_launch(void* const* d_in, const int* in_sizes, int n_in,
                              void* d_out, int out_size, void* d_ws, size_t ws_size,
                              hipStream_t stream) {
    const float* x = (const float*)d_in[0];
    const int* ei = (const int*)d_in[1];
    const float* lam_raw = (const float*)d_in[4];

    float* deg = (float*)d_ws;        // [8192]
    float* sq = deg + NN;             // [8192]

    hipMemsetAsync(d_ws, 0, NN * sizeof(float), stream);         // zero deg
    hipMemsetAsync(d_out, 0, NG * NG * sizeof(float), stream);   // diagonal = 0
    deg_kernel<<<NE / 256, 256, 0, stream>>>(ei, deg);
    sq_kernel<<<NN / 256, 256, 0, stream>>>(x, sq);
    sim_kernel<<<NPAIR, 256, 0, stream>>>(x, deg, sq, lam_raw, (float*)d_out);
}

// Round 3
// 95.082 us; speedup vs baseline: 2.1238x; 1.0759x over previous
//
#include <hip/hip_runtime.h>
#include <math.h>

#define NG 64
#define NPG 128
#define DF 64
#define NN (NG * NPG)   // 8192
#define NE 131072
#define NPAIR 2016      // 64*63/2 unordered pairs g<h

typedef __attribute__((ext_vector_type(8))) short short8;   // 8 bf16 = 4 VGPRs
typedef __attribute__((ext_vector_type(4))) float f32x4;

static __device__ __forceinline__ unsigned short f2bf(float f) {
    unsigned u = __builtin_bit_cast(unsigned, f);
    return (unsigned short)((u + 0x7FFFu + ((u >> 16) & 1u)) >> 16);  // RNE
}

// ---- prep: zero deg, zero out-diagonal, per-node sq, x -> bf16 (xb).
// one thread per float4 of x; 16 consecutive lanes = one node.
__global__ void prep_kernel(const float* __restrict__ x, float* __restrict__ deg,
                            float* __restrict__ sq, unsigned short* __restrict__ xb,
                            float* __restrict__ out) {
    int i = blockIdx.x * 256 + threadIdx.x;       // 0..131071
    if (i < NN) deg[i] = 0.f;
    if (i < NG) out[i * (NG + 1)] = 0.f;          // diagonal of dist = 0

    float4 v = ((const float4*)x)[i];
    float s = v.x * v.x;
    s = fmaf(v.y, v.y, s);
    s = fmaf(v.z, v.z, s);
    s = fmaf(v.w, v.w, s);
    s += __shfl_xor(s, 1, 64);
    s += __shfl_xor(s, 2, 64);
    s += __shfl_xor(s, 4, 64);
    s += __shfl_xor(s, 8, 64);
    if ((i & 15) == 0) sq[i >> 4] = s;

    ushort4 b;
    b.x = f2bf(v.x); b.y = f2bf(v.y); b.z = f2bf(v.z); b.w = f2bf(v.w);
    ((ushort4*)xb)[i] = b;
}

// ---- degree: one float atomicAdd per edge endpoint (exact for small ints)
__global__ void deg_kernel(const int* __restrict__ ei, float* __restrict__ deg) {
    int i = blockIdx.x * 256 + threadIdx.x;
    atomicAdd(&deg[ei[i]], 1.0f);
    atomicAdd(&deg[ei[NE + i]], 1.0f);
}

// ---- main: one block per unordered pair (g<h). Gram via bf16 MFMA 16x16x32.
// bf16 staged from precomputed xb; LDS rows = 64 bf16 (8 granules of 16B),
// granule XOR-swizzled (phys = gq ^ (row&7)) -> 2-way-max LDS aliasing (free).
// Epilogue in z-space (exp AFTER max: exp monotone).
__global__ __launch_bounds__(256, 4) void sim_kernel(
    const unsigned short* __restrict__ xb, const float* __restrict__ deg,
    const float* __restrict__ sq, const float* __restrict__ lam_raw,
    float* __restrict__ out) {
    __shared__ __align__(16) unsigned short As[NPG * DF];
    __shared__ __align__(16) unsigned short Bs[NPG * DF];
    __shared__ float dA[NPG], qA[NPG], dB[NPG], qB[NPG];
    __shared__ float rowpart[4];
    __shared__ float colpart[4 * NPG];
    __shared__ float redbuf[2];

    const int t = threadIdx.x;

    // decode blockIdx -> (g,h), g<h (triangular, reversed enumeration)
    int j = (NPAIR - 1) - (int)blockIdx.x;
    int r = (int)((sqrtf((float)(8 * j + 1)) - 1.0f) * 0.5f);
    while ((r + 1) * (r + 2) / 2 <= j) ++r;
    while (r * (r + 1) / 2 > j) --r;
    const int g = 62 - r;
    const int h = 63 - (j - r * (r + 1) / 2);

    // stage bf16 blocks: 1024 16B granules each, coalesced, XOR-swizzled
    const uint4* ga = (const uint4*)(xb + (size_t)g * NPG * DF);
    const uint4* gb = (const uint4*)(xb + (size_t)h * NPG * DF);
    uint4* sa = (uint4*)As;
    uint4* sb = (uint4*)Bs;
#pragma unroll
    for (int it = 0; it < 4; ++it) {
        int gid = it * 256 + t;          // 0..1023
        int rr = gid >> 3, cc = gid & 7;
        int phys = rr * 8 + (cc ^ (rr & 7));
        sa[phys] = ga[gid];
        sb[phys] = gb[gid];
    }
    if (t < 128) {
        dA[t] = deg[g * NPG + t];
        qA[t] = sq[g * NPG + t];
    } else {
        int u = t - 128;
        dB[u] = deg[h * NPG + u];
        qB[u] = sq[h * NPG + u];
    }
    __syncthreads();

    const int L = t & 63, w = t >> 6;
    const int tx = L & 15, q = L >> 4;
    const int sw = tx & 7;               // row&7 == tx&7 for all fragment rows

    f32x4 acc[2][8];
#pragma unroll
    for (int tr = 0; tr < 2; ++tr)
#pragma unroll
        for (int tc = 0; tc < 8; ++tc) acc[tr][tc] = (f32x4){0.f, 0.f, 0.f, 0.f};

    // K = 64 = 2 halves of 32. A/B elem: row = lane&15, k = quad*8+j.
#pragma unroll
    for (int kh = 0; kh < 2; ++kh) {
        int phg = (kh * 4 + q) ^ sw;     // swizzled granule for this quad
        int ra0 = w * 32 + tx, ra1 = ra0 + 16;
        short8 a0 = *(const short8*)&As[ra0 * DF + phg * 8];
        short8 a1 = *(const short8*)&As[ra1 * DF + phg * 8];
        short8 bfr[8];
#pragma unroll
        for (int tc = 0; tc < 8; ++tc)
            bfr[tc] = *(const short8*)&Bs[(tc * 16 + tx) * DF + phg * 8];
#pragma unroll
        for (int tc = 0; tc < 8; ++tc)
            acc[0][tc] = __builtin_amdgcn_mfma_f32_16x16x32_bf16(a0, bfr[tc], acc[0][tc], 0, 0, 0);
#pragma unroll
        for (int tc = 0; tc < 8; ++tc)
            acc[1][tc] = __builtin_amdgcn_mfma_f32_16x16x32_bf16(a1, bfr[tc], acc[1][tc], 0, 0, 0);
    }

    // C/D layout: col = lane&15, row = quad*4 + reg
    // z = 2*(G + da*db) - (qa + da^2) - (qb + db^2)  [= 2G - qa - qb - (da-db)^2]
    float Ai[2][4], dav[2][4], Bj[8], dbv[8];
#pragma unroll
    for (int tr = 0; tr < 2; ++tr)
#pragma unroll
        for (int v = 0; v < 4; ++v) {
            int ra = w * 32 + tr * 16 + q * 4 + v;
            float dv = dA[ra];
            dav[tr][v] = dv;
            Ai[tr][v] = fmaf(dv, dv, qA[ra]);
        }
#pragma unroll
    for (int tc = 0; tc < 8; ++tc) {
        int cb = tc * 16 + tx;
        float dv = dB[cb];
        dbv[tc] = dv;
        Bj[tc] = fmaf(dv, dv, qB[cb]);
    }

    float zr[2][4], zc[8];
#pragma unroll
    for (int tr = 0; tr < 2; ++tr)
#pragma unroll
        for (int v = 0; v < 4; ++v) zr[tr][v] = -3.0e38f;
#pragma unroll
    for (int tc = 0; tc < 8; ++tc) zc[tc] = -3.0e38f;

#pragma unroll
    for (int tr = 0; tr < 2; ++tr)
#pragma unroll
        for (int tc = 0; tc < 8; ++tc)
#pragma unroll
            for (int v = 0; v < 4; ++v) {
                float m = fmaf(dav[tr][v], dbv[tc], acc[tr][tc][v]);
                float z = fmaf(2.f, m, -(Ai[tr][v] + Bj[tc]));
                zr[tr][v] = fmaxf(zr[tr][v], z);
                zc[tc] = fmaxf(zc[tc], z);
            }

    // row z-maxes: butterfly over the 16 cols, THEN exp
#pragma unroll
    for (int off = 1; off < 16; off <<= 1)
#pragma unroll
        for (int tr = 0; tr < 2; ++tr)
#pragma unroll
            for (int v = 0; v < 4; ++v)
                zr[tr][v] = fmaxf(zr[tr][v], __shfl_xor(zr[tr][v], off, 64));
    float rsum = 0.f;
#pragma unroll
    for (int tr = 0; tr < 2; ++tr)
#pragma unroll
        for (int v = 0; v < 4; ++v) rsum += __expf(zr[tr][v]);
    rsum += __shfl_xor(rsum, 16, 64);
    rsum += __shfl_xor(rsum, 32, 64);   // sum over this wave's 32 row-maxes
    if (L == 0) rowpart[w] = rsum;

    // col z-maxes: butterfly across quads, then LDS across waves (z-space)
#pragma unroll
    for (int off = 16; off < 64; off <<= 1)
#pragma unroll
        for (int tc = 0; tc < 8; ++tc)
            zc[tc] = fmaxf(zc[tc], __shfl_xor(zc[tc], off, 64));
    if (L < 16) {
#pragma unroll
        for (int tc = 0; tc < 8; ++tc)
            colpart[w * NPG + tc * 16 + L] = zc[tc];
    }
    __syncthreads();

    if (t < 128) {
        float cm = colpart[t];
#pragma unroll
        for (int w2 = 1; w2 < 4; ++w2) cm = fmaxf(cm, colpart[w2 * NPG + t]);
        cm = __expf(cm);                 // exp after the full 128-row max
#pragma unroll
        for (int off = 1; off < 64; off <<= 1)
            cm += __shfl_xor(cm, off, 64);
        if ((t & 63) == 0) redbuf[t >> 6] = cm;
    }
    __syncthreads();
    if (t == 0) {
        float mrow = rowpart[0] + rowpart[1] + rowpart[2] + rowpart[3];
        float mcol = redbuf[0] + redbuf[1];
        float M = 0.5f * (mrow + mcol);   // final symmetrized match[g,h]
        float lam = log1pf(expf(lam_raw[0]));
        float dv = lam * ((float)NPG - M);
        out[g * NG + h] = dv;
        out[h * NG + g] = dv;
    }
}

extern "C" void kernel_launch(void* const* d_in, const int* in_sizes, int n_in,
                              void* d_out, int out_size, void* d_ws, size_t ws_size,
                              hipStream_t stream) {
    const float* x = (const float*)d_in[0];
    const int* ei = (const int*)d_in[1];
    const float* lam_raw = (const float*)d_in[4];

    float* deg = (float*)d_ws;                     // [8192]
    float* sq = deg + NN;                          // [8192]
    unsigned short* xb = (unsigned short*)(sq + NN);  // [8192*64] bf16

    prep_kernel<<<(NN * DF / 4) / 256, 256, 0, stream>>>(x, deg, sq, xb, (float*)d_out);
    deg_kernel<<<NE / 256, 256, 0, stream>>>(ei, deg);
    sim_kernel<<<NPAIR, 256, 0, stream>>>(xb, deg, sq, lam_raw, (float*)d_out);
}

// Round 4
// 93.982 us; speedup vs baseline: 2.1487x; 1.0117x over previous
//
#include <hip/hip_runtime.h>
#include <math.h>

#define NG 64
#define NPG 128
#define DF 64
#define NN (NG * NPG)   // 8192
#define NE 131072
#define NPAIR 2016      // 64*63/2 unordered pairs g<h
#define DEGB 32         // histogram blocks

typedef __attribute__((ext_vector_type(8))) short short8;   // 8 bf16 = 4 VGPRs
typedef __attribute__((ext_vector_type(4))) float f32x4;

static __device__ __forceinline__ unsigned short f2bf(float f) {
    unsigned u = __builtin_bit_cast(unsigned, f);
    return (unsigned short)((u + 0x7FFFu + ((u >> 16) & 1u)) >> 16);  // RNE
}

// ---- phase A: per-block LDS histogram of edge endpoints. NO global atomics:
// each block writes its own 8192-entry partial count (coalesced stores).
__global__ __launch_bounds__(256) void degpart_kernel(const int* __restrict__ ei,
                                                      unsigned* __restrict__ degpart) {
    __shared__ unsigned hist[NN];
    const int t = threadIdx.x, b = blockIdx.x;
#pragma unroll
    for (int k = t; k < NN; k += 256) hist[k] = 0u;
    __syncthreads();
    const int base = b * (2 * NE / DEGB);      // 8192 endpoints per block
#pragma unroll
    for (int k = 0; k < 2 * NE / DEGB; k += 256)
        atomicAdd(&hist[ei[base + k + t]], 1u);   // LDS atomic, intra-CU
    __syncthreads();
#pragma unroll
    for (int k = t; k < NN; k += 256)
        degpart[b * NN + k] = hist[k];
}

// ---- prep: fold deg partials, zero out-diagonal, per-node sq, x -> bf16.
// one thread per float4 of x; 16 consecutive lanes = one node.
__global__ void prep_kernel(const float* __restrict__ x,
                            const unsigned* __restrict__ degpart,
                            float* __restrict__ deg,
                            float* __restrict__ sq, unsigned short* __restrict__ xb,
                            float* __restrict__ out) {
    int i = blockIdx.x * 256 + threadIdx.x;       // 0..131071
    if (i < NN) {
        unsigned s = 0u;
#pragma unroll
        for (int k = 0; k < DEGB; ++k) s += degpart[k * NN + i];
        deg[i] = (float)s;
    }
    if (i < NG) out[i * (NG + 1)] = 0.f;          // diagonal of dist = 0

    float4 v = ((const float4*)x)[i];
    float s = v.x * v.x;
    s = fmaf(v.y, v.y, s);
    s = fmaf(v.z, v.z, s);
    s = fmaf(v.w, v.w, s);
    s += __shfl_xor(s, 1, 64);
    s += __shfl_xor(s, 2, 64);
    s += __shfl_xor(s, 4, 64);
    s += __shfl_xor(s, 8, 64);
    if ((i & 15) == 0) sq[i >> 4] = s;

    ushort4 b;
    b.x = f2bf(v.x); b.y = f2bf(v.y); b.z = f2bf(v.z); b.w = f2bf(v.w);
    ((ushort4*)xb)[i] = b;
}

// ---- main: one block per unordered pair (g<h). Gram via bf16 MFMA 16x16x32.
// bf16 staged from precomputed xb; LDS rows = 64 bf16 (8 granules of 16B),
// granule XOR-swizzled (phys = gq ^ (row&7)) -> 2-way-max LDS aliasing (free).
// Epilogue in z-space (exp AFTER max: exp monotone).
__global__ __launch_bounds__(256, 4) void sim_kernel(
    const unsigned short* __restrict__ xb, const float* __restrict__ deg,
    const float* __restrict__ sq, const float* __restrict__ lam_raw,
    float* __restrict__ out) {
    __shared__ __align__(16) unsigned short As[NPG * DF];
    __shared__ __align__(16) unsigned short Bs[NPG * DF];
    __shared__ float dA[NPG], qA[NPG], dB[NPG], qB[NPG];
    __shared__ float rowpart[4];
    __shared__ float colpart[4 * NPG];
    __shared__ float redbuf[2];

    const int t = threadIdx.x;

    // decode blockIdx -> (g,h), g<h (triangular, reversed enumeration)
    int j = (NPAIR - 1) - (int)blockIdx.x;
    int r = (int)((sqrtf((float)(8 * j + 1)) - 1.0f) * 0.5f);
    while ((r + 1) * (r + 2) / 2 <= j) ++r;
    while (r * (r + 1) / 2 > j) --r;
    const int g = 62 - r;
    const int h = 63 - (j - r * (r + 1) / 2);

    // stage bf16 blocks: 1024 16B granules each, coalesced, XOR-swizzled
    const uint4* ga = (const uint4*)(xb + (size_t)g * NPG * DF);
    const uint4* gb = (const uint4*)(xb + (size_t)h * NPG * DF);
    uint4* sa = (uint4*)As;
    uint4* sb = (uint4*)Bs;
#pragma unroll
    for (int it = 0; it < 4; ++it) {
        int gid = it * 256 + t;          // 0..1023
        int rr = gid >> 3, cc = gid & 7;
        int phys = rr * 8 + (cc ^ (rr & 7));
        sa[phys] = ga[gid];
        sb[phys] = gb[gid];
    }
    if (t < 128) {
        dA[t] = deg[g * NPG + t];
        qA[t] = sq[g * NPG + t];
    } else {
        int u = t - 128;
        dB[u] = deg[h * NPG + u];
        qB[u] = sq[h * NPG + u];
    }
    __syncthreads();

    const int L = t & 63, w = t >> 6;
    const int tx = L & 15, q = L >> 4;
    const int sw = tx & 7;               // row&7 == tx&7 for all fragment rows

    f32x4 acc[2][8];
#pragma unroll
    for (int tr = 0; tr < 2; ++tr)
#pragma unroll
        for (int tc = 0; tc < 8; ++tc) acc[tr][tc] = (f32x4){0.f, 0.f, 0.f, 0.f};

    // K = 64 = 2 halves of 32. A/B elem: row = lane&15, k = quad*8+j.
#pragma unroll
    for (int kh = 0; kh < 2; ++kh) {
        int phg = (kh * 4 + q) ^ sw;     // swizzled granule for this quad
        int ra0 = w * 32 + tx, ra1 = ra0 + 16;
        short8 a0 = *(const short8*)&As[ra0 * DF + phg * 8];
        short8 a1 = *(const short8*)&As[ra1 * DF + phg * 8];
        short8 bfr[8];
#pragma unroll
        for (int tc = 0; tc < 8; ++tc)
            bfr[tc] = *(const short8*)&Bs[(tc * 16 + tx) * DF + phg * 8];
#pragma unroll
        for (int tc = 0; tc < 8; ++tc)
            acc[0][tc] = __builtin_amdgcn_mfma_f32_16x16x32_bf16(a0, bfr[tc], acc[0][tc], 0, 0, 0);
#pragma unroll
        for (int tc = 0; tc < 8; ++tc)
            acc[1][tc] = __builtin_amdgcn_mfma_f32_16x16x32_bf16(a1, bfr[tc], acc[1][tc], 0, 0, 0);
    }

    // C/D layout: col = lane&15, row = quad*4 + reg
    // z = 2*(G + da*db) - (qa + da^2) - (qb + db^2)  [= 2G - qa - qb - (da-db)^2]
    float Ai[2][4], dav[2][4], Bj[8], dbv[8];
#pragma unroll
    for (int tr = 0; tr < 2; ++tr)
#pragma unroll
        for (int v = 0; v < 4; ++v) {
            int ra = w * 32 + tr * 16 + q * 4 + v;
            float dv = dA[ra];
            dav[tr][v] = dv;
            Ai[tr][v] = fmaf(dv, dv, qA[ra]);
        }
#pragma unroll
    for (int tc = 0; tc < 8; ++tc) {
        int cb = tc * 16 + tx;
        float dv = dB[cb];
        dbv[tc] = dv;
        Bj[tc] = fmaf(dv, dv, qB[cb]);
    }

    float zr[2][4], zc[8];
#pragma unroll
    for (int tr = 0; tr < 2; ++tr)
#pragma unroll
        for (int v = 0; v < 4; ++v) zr[tr][v] = -3.0e38f;
#pragma unroll
    for (int tc = 0; tc < 8; ++tc) zc[tc] = -3.0e38f;

#pragma unroll
    for (int tr = 0; tr < 2; ++tr)
#pragma unroll
        for (int tc = 0; tc < 8; ++tc)
#pragma unroll
            for (int v = 0; v < 4; ++v) {
                float m = fmaf(dav[tr][v], dbv[tc], acc[tr][tc][v]);
                float z = fmaf(2.f, m, -(Ai[tr][v] + Bj[tc]));
                zr[tr][v] = fmaxf(zr[tr][v], z);
                zc[tc] = fmaxf(zc[tc], z);
            }

    // row z-maxes: butterfly over the 16 cols, THEN exp
#pragma unroll
    for (int off = 1; off < 16; off <<= 1)
#pragma unroll
        for (int tr = 0; tr < 2; ++tr)
#pragma unroll
            for (int v = 0; v < 4; ++v)
                zr[tr][v] = fmaxf(zr[tr][v], __shfl_xor(zr[tr][v], off, 64));
    float rsum = 0.f;
#pragma unroll
    for (int tr = 0; tr < 2; ++tr)
#pragma unroll
        for (int v = 0; v < 4; ++v) rsum += __expf(zr[tr][v]);
    rsum += __shfl_xor(rsum, 16, 64);
    rsum += __shfl_xor(rsum, 32, 64);   // sum over this wave's 32 row-maxes
    if (L == 0) rowpart[w] = rsum;

    // col z-maxes: butterfly across quads, then LDS across waves (z-space)
#pragma unroll
    for (int off = 16; off < 64; off <<= 1)
#pragma unroll
        for (int tc = 0; tc < 8; ++tc)
            zc[tc] = fmaxf(zc[tc], __shfl_xor(zc[tc], off, 64));
    if (L < 16) {
#pragma unroll
        for (int tc = 0; tc < 8; ++tc)
            colpart[w * NPG + tc * 16 + L] = zc[tc];
    }
    __syncthreads();

    if (t < 128) {
        float cm = colpart[t];
#pragma unroll
        for (int w2 = 1; w2 < 4; ++w2) cm = fmaxf(cm, colpart[w2 * NPG + t]);
        cm = __expf(cm);                 // exp after the full 128-row max
#pragma unroll
        for (int off = 1; off < 64; off <<= 1)
            cm += __shfl_xor(cm, off, 64);
        if ((t & 63) == 0) redbuf[t >> 6] = cm;
    }
    __syncthreads();
    if (t == 0) {
        float mrow = rowpart[0] + rowpart[1] + rowpart[2] + rowpart[3];
        float mcol = redbuf[0] + redbuf[1];
        float M = 0.5f * (mrow + mcol);   // final symmetrized match[g,h]
        float lam = log1pf(expf(lam_raw[0]));
        float dv = lam * ((float)NPG - M);
        out[g * NG + h] = dv;
        out[h * NG + g] = dv;
    }
}

extern "C" void kernel_launch(void* const* d_in, const int* in_sizes, int n_in,
                              void* d_out, int out_size, void* d_ws, size_t ws_size,
                              hipStream_t stream) {
    const float* x = (const float*)d_in[0];
    const int* ei = (const int*)d_in[1];
    const float* lam_raw = (const float*)d_in[4];

    unsigned* degpart = (unsigned*)d_ws;                 // [32*8192] u32
    float* deg = (float*)(degpart + DEGB * NN);          // [8192]
    float* sq = deg + NN;                                // [8192]
    unsigned short* xb = (unsigned short*)(sq + NN);     // [8192*64] bf16

    degpart_kernel<<<DEGB, 256, 0, stream>>>(ei, degpart);
    prep_kernel<<<(NN * DF / 4) / 256, 256, 0, stream>>>(x, degpart, deg, sq, xb, (float*)d_out);
    sim_kernel<<<NPAIR, 256, 0, stream>>>(xb, deg, sq, lam_raw, (float*)d_out);
}